// Round 5
// baseline (297.825 us; speedup 1.0000x reference)
//
#include <hip/hip_runtime.h>

// LSTM B=2048, T=512, I=1, H=64, O=1 (PyTorch gate order i,f,g,o).
// j-partition design, ONE barrier per step, gates never leave registers:
//   WG = 256 thr (4 waves) owns 16 batches; grid = 128.
//   G^T = W @ h^T: A = W fragments (VGPRs, loaded once), B = h (LDS, fp16,
//   XOR-swizzled, double-buffered 2x2KB). Wave wv computes C-tiles {g*4+wv},
//   g = gate block -> after 8 MFMAs lane ln holds ALL 4 gates of 4 states
//   (batch = ln&15, j = 16wv+4grp+reg) in acc registers. Activations on all
//   64 lanes, 4 states/lane; h packed to one ds_write_b64 (consecutive j).
// Gate pre-scaling: W,b,w_ih rows scaled by -log2e (i,f,o) / -2log2e (g)
//   so sigmoid/tanh = rcp(1+exp2(g)) with no pre-multiply (saturating).
// x read from global per-lane (float4 per 4 steps, prefetched) - no staging.

typedef float    f32x4 __attribute__((ext_vector_type(4)));
typedef _Float16 f16x8 __attribute__((ext_vector_type(8)));
typedef _Float16 f16x4 __attribute__((ext_vector_type(4)));

namespace {
constexpr int Bsz = 2048;
constexpr int Tsz = 512;
constexpr int NBW = 16;   // batches per workgroup
}

__device__ __forceinline__ float rcp_f(float v)  { return __builtin_amdgcn_rcpf(v); }
__device__ __forceinline__ float exp2_f(float v) { return __builtin_amdgcn_exp2f(v); }

// gs = -log2e * gate  ->  sigmoid(gate); saturates correctly at +-inf
__device__ __forceinline__ float sigm_s(float gs) {
    return rcp_f(1.0f + exp2_f(gs));
}
// gs = -2log2e * gate ->  tanh(gate)
__device__ __forceinline__ float tanh_s(float gs) {
    return fmaf(2.0f, rcp_f(1.0f + exp2_f(gs)), -1.0f);
}
// plain tanh for cell state
__device__ __forceinline__ float tanh_plain(float v) {
    return fmaf(2.0f, rcp_f(1.0f + exp2_f(v * -2.88539008178f)), -1.0f);
}

__global__ __launch_bounds__(256, 1)
void lstm_v5(const float* __restrict__ x,      // [B,T]
             const float* __restrict__ w_ih,   // [256]
             const float* __restrict__ w_hh,   // [256,64]
             const float* __restrict__ b_ih,   // [256]
             const float* __restrict__ b_hh,   // [256]
             const float* __restrict__ w_lin,  // [64]
             const float* __restrict__ b_lin,  // [1]
             float* __restrict__ out)          // [B]
{
    // double-buffered h in MFMA-B layout: row = batch (16), 128 B of k (fp16),
    // XOR swizzle byte ^= (row&7)<<4 within each row.
    __shared__ __align__(16) char hAb[2][16 * 128];   // 4 KB total

    const int tid = threadIdx.x;
    const int wv  = tid >> 6;
    const int ln  = tid & 63;
    const int row = ln & 15;     // batch index within WG (B-frag col, C col)
    const int grp = ln >> 4;
    const int b0  = blockIdx.x * NBW;

    constexpr float LOG2E = 1.44269504089f;

    // ---- A-operand W fragments (one-time), pre-scaled per gate block ----
    // tile g covers gates [g*64 + 16*wv, +16). A-frag: m = row, k = kc*32+grp*8+e
    f16x8 Wf[4][2];
    float wihc[4][4], biasc[4][4];
    #pragma unroll
    for (int g = 0; g < 4; ++g) {
        const float s = (g == 2) ? (-2.0f * LOG2E) : (-LOG2E);
        const float* wrow = w_hh + (size_t)(g * 64 + 16 * wv + row) * 64;
        #pragma unroll
        for (int kc = 0; kc < 2; ++kc) {
            const float4 a = ((const float4*)wrow)[kc * 8 + grp * 2 + 0];
            const float4 b = ((const float4*)wrow)[kc * 8 + grp * 2 + 1];
            f16x8 w;
            w[0] = (_Float16)(a.x * s); w[1] = (_Float16)(a.y * s);
            w[2] = (_Float16)(a.z * s); w[3] = (_Float16)(a.w * s);
            w[4] = (_Float16)(b.x * s); w[5] = (_Float16)(b.y * s);
            w[6] = (_Float16)(b.z * s); w[7] = (_Float16)(b.w * s);
            Wf[g][kc] = w;
        }
        // C-init constants for this lane's C rows: gate = g*64 + 16wv + 4grp + reg
        #pragma unroll
        for (int reg = 0; reg < 4; ++reg) {
            const int gt = g * 64 + 16 * wv + 4 * grp + reg;
            wihc[g][reg]  = w_ih[gt] * s;
            biasc[g][reg] = (b_ih[gt] + b_hh[gt]) * s;
        }
    }

    // w_lin for this lane's 4 j's
    float wlinc[4];
    #pragma unroll
    for (int reg = 0; reg < 4; ++reg)
        wlinc[reg] = w_lin[16 * wv + 4 * grp + reg];

    // ---- B-frag read offsets (batch = row): k-chunk kc at kc*64 + grp*16 ----
    const int sw    = (row & 7) << 4;
    const int boff0 = row * 128 + ((0 * 64 + grp * 16) ^ sw);
    const int boff1 = row * 128 + ((1 * 64 + grp * 16) ^ sw);
    // h-write: 4 consecutive j = 16wv + 4grp + (0..3) -> 8B at byte 32wv+8grp
    const int hwoff = row * 128 + (((32 * wv + 8 * grp)) ^ sw);

    // zero h buffer 0 (h_0 = 0); buffer 1 is fully written before first read
    reinterpret_cast<float2*>(&hAb[0][0])[tid] = make_float2(0.0f, 0.0f);

    // per-lane x pointer (batch = row), float4 per 4 timesteps, prefetched
    const float4* xp4 = (const float4*)(x + (size_t)(b0 + row) * Tsz);
    float4 xcur = xp4[0];

    float c[4] = {0.f, 0.f, 0.f, 0.f};
    float h[4] = {0.f, 0.f, 0.f, 0.f};

    __syncthreads();

    for (int t4 = 0; t4 < Tsz / 4; ++t4) {
        const float4 xnxt = xp4[(t4 < Tsz / 4 - 1) ? (t4 + 1) : (Tsz / 4 - 1)];

        #pragma unroll
        for (int s = 0; s < 4; ++s) {
            const int rp = s & 1;          // t = t4*4+s, read parity = t&1
            const int wp = rp ^ 1;
            const float xs = (s == 0) ? xcur.x : (s == 1) ? xcur.y
                           : (s == 2) ? xcur.z : xcur.w;

            const f16x8 B0 = *(const f16x8*)(hAb[rp] + boff0);
            const f16x8 B1 = *(const f16x8*)(hAb[rp] + boff1);

            f32x4 acc[4];
            #pragma unroll
            for (int g = 0; g < 4; ++g) {
                #pragma unroll
                for (int reg = 0; reg < 4; ++reg)
                    acc[g][reg] = fmaf(xs, wihc[g][reg], biasc[g][reg]);
            }
            #pragma unroll
            for (int g = 0; g < 4; ++g)
                acc[g] = __builtin_amdgcn_mfma_f32_16x16x32_f16(Wf[g][0], B0, acc[g], 0, 0, 0);
            #pragma unroll
            for (int g = 0; g < 4; ++g)
                acc[g] = __builtin_amdgcn_mfma_f32_16x16x32_f16(Wf[g][1], B1, acc[g], 0, 0, 0);

            // activations: 4 states/lane, all gates in-register (pre-scaled)
            f16x4 hp;
            #pragma unroll
            for (int reg = 0; reg < 4; ++reg) {
                const float ig = sigm_s(acc[0][reg]);
                const float fg = sigm_s(acc[1][reg]);
                const float tg = tanh_s(acc[2][reg]);
                const float og = sigm_s(acc[3][reg]);
                c[reg] = fmaf(fg, c[reg], ig * tg);
                h[reg] = og * tanh_plain(c[reg]);
                hp[reg] = (_Float16)h[reg];
            }
            *(f16x4*)(hAb[wp] + hwoff) = hp;   // one b64 write

            __syncthreads();                   // the ONLY barrier per step
        }
        xcur = xnxt;
    }

    // ---- out[b0+b] = sum_j h[b][j]*w_lin[j] + b_lin ----
    float p = h[0] * wlinc[0] + h[1] * wlinc[1] + h[2] * wlinc[2] + h[3] * wlinc[3];
    p += __shfl_xor(p, 16, 64);   // lanes with same batch (row) differ in grp
    p += __shfl_xor(p, 32, 64);
    float* part = reinterpret_cast<float*>(&hAb[0][0]);
    if (ln < 16) part[wv * 16 + ln] = p;   // after last loop barrier: safe
    __syncthreads();
    if (tid < 16)
        out[b0 + tid] = part[tid] + part[16 + tid] + part[32 + tid] +
                        part[48 + tid] + b_lin[0];
}

extern "C" void kernel_launch(void* const* d_in, const int* in_sizes, int n_in,
                              void* d_out, int out_size, void* d_ws, size_t ws_size,
                              hipStream_t stream) {
    const float* x     = (const float*)d_in[0];
    const float* w_ih  = (const float*)d_in[1];
    const float* w_hh  = (const float*)d_in[2];
    const float* b_ih  = (const float*)d_in[3];
    const float* b_hh  = (const float*)d_in[4];
    const float* w_lin = (const float*)d_in[5];
    const float* b_lin = (const float*)d_in[6];
    float* out = (float*)d_out;

    dim3 grid(Bsz / NBW);   // 128
    dim3 block(256);
    lstm_v5<<<grid, block, 0, stream>>>(x, w_ih, w_hh, b_ih, b_hh,
                                        w_lin, b_lin, out);
}